// Round 5
// baseline (81.712 us; speedup 1.0000x reference)
//
#include <hip/hip_runtime.h>
#include <hip/hip_bf16.h>

#define N_ 256
#define C_ 128
#define S_ 961
#define K_ 64
#define TS 64
#define NTILE 16
#define NTHREADS 512

typedef __attribute__((ext_vector_type(4))) float f32x4;
typedef __attribute__((ext_vector_type(8))) short bf16x8;
typedef __attribute__((ext_vector_type(4))) unsigned short us4;

#define MFMA16(a, b, c) __builtin_amdgcn_mfma_f32_16x16x32_bf16((a), (b), (c), 0, 0, 0)

// truncation split: f = hi + lo with |err| <= 2^-16 |f| ; 4 VALU ops
static __device__ __forceinline__ void split_bf(float f, unsigned short& h, unsigned short& l) {
    unsigned int u = __builtin_bit_cast(unsigned int, f);
    unsigned int ur = u & 0xFFFF0000u;
    h = (unsigned short)(ur >> 16);
    float r = f - __builtin_bit_cast(float, ur);
    l = (unsigned short)(__builtin_bit_cast(unsigned int, r) >> 16);
}

template <int CTRL>
static __device__ __forceinline__ float dpp_add(float v) {
    int sw = __builtin_amdgcn_update_dpp(0, __builtin_bit_cast(int, v), CTRL, 0xF, 0xF, true);
    return v + __builtin_bit_cast(float, sw);
}
// sum over all 64 lanes, broadcast (4 VALU-DPP + 2 shfl)
static __device__ __forceinline__ float wave_sum64(float v) {
    v = dpp_add<0xB1>(v);    // quad_perm xor1
    v = dpp_add<0x4E>(v);    // quad_perm xor2
    v = dpp_add<0x141>(v);   // row_half_mirror
    v = dpp_add<0x140>(v);   // row_mirror
    v += __shfl_xor(v, 16);
    v += __shfl_xor(v, 32);
    return v;
}

__global__ __launch_bounds__(NTHREADS, 1) void vlad_mfma_kernel(
    const float* __restrict__ x,       // [N,C,S]
    const float* __restrict__ conv_w,  // [K,C]
    const float* __restrict__ cent,    // [K,C]
    const float* __restrict__ aw,      // [C]
    const float* __restrict__ ab,      // [1]
    float* __restrict__ out)           // [N, K*C]
{
    __shared__ union {
        unsigned short xs[2][2][C_][72];   // [buf][hi/lo][c][s] (pitch 144B)
        float vl[K_][130];
    } sxv;
    __shared__ float s_d[K_][68];               // logits (pitch 272B)
    __shared__ unsigned short s_u[2][K_][72];   // [hi/lo][k][s]
    __shared__ float s_ared[2][8][68];          // [ssq/hd][wave][s]
    __shared__ float s_wred[8][K_];
    __shared__ float s_wsum[K_], s_rs[K_];
    __shared__ float s_fin;

    const int tid = threadIdx.x;
    const int n = blockIdx.x;
    const int lane = tid & 63;
    const int w = tid >> 6;          // wave 0..7
    const int la = lane & 15;
    const int lg = lane >> 4;
    const float bias = ab[0];
    const float* xn = x + (size_t)n * (C_ * S_);

    // staging mapping: 4c x 4s per thread
    const int cb = tid >> 4;
    const int c0 = cb * 4;
    const int s0l = (tid & 15) * 4;

    float awr[4];
    #pragma unroll
    for (int r = 0; r < 4; ++r) awr[r] = aw[c0 + r];

    // GEMM1: n-tile nt1, m-tiles {mtb, mtb+1}
    const int nt1 = w & 3;
    const int mtb = (w >> 2) * 2;
    bf16x8 cwhi[2][4], cwlo[2][4];
    #pragma unroll
    for (int m2 = 0; m2 < 2; ++m2) {
        int row = la + 16 * (mtb + m2);
        #pragma unroll
        for (int cc = 0; cc < 4; ++cc) {
            const float* p = conv_w + row * C_ + 8 * lg + 32 * cc;
            #pragma unroll
            for (int i = 0; i < 8; ++i) {
                unsigned short h, l;
                split_bf(p[i], h, l);
                cwhi[m2][cc][i] = (short)h;
                cwlo[m2][cc][i] = (short)l;
            }
        }
    }

    // GEMM2: 2 m-tiles x 2 c-tiles per wave
    const int mtb2 = (w & 1) * 2;
    const int ctb2 = (w >> 1) * 2;
    f32x4 acc2[2][2];
    #pragma unroll
    for (int m = 0; m < 2; ++m)
        #pragma unroll
        for (int ci = 0; ci < 2; ++ci) acc2[m][ci] = (f32x4){0.f, 0.f, 0.f, 0.f};

    float wpart = 0.f;
    float pxA[4][4], pxB[4][4];

    // preload px(0)
    #pragma unroll
    for (int r = 0; r < 4; ++r) {
        const float* pr = xn + (size_t)(c0 + r) * S_ + s0l;
        pxA[r][0] = pr[0]; pxA[r][1] = pr[1]; pxA[r][2] = pr[2]; pxA[r][3] = pr[3];
    }

#define GEMM2_STEP(SB)                                                          \
    {                                                                           \
        _Pragma("unroll") for (int sc = 0; sc < 2; ++sc) {                      \
            bf16x8 ah[2], al8[2];                                               \
            _Pragma("unroll") for (int m = 0; m < 2; ++m) {                     \
                ah[m]  = *(const bf16x8*)&s_u[0][la + 16*(mtb2+m)][8*lg + 32*sc]; \
                al8[m] = *(const bf16x8*)&s_u[1][la + 16*(mtb2+m)][8*lg + 32*sc]; \
            }                                                                   \
            _Pragma("unroll") for (int ci = 0; ci < 2; ++ci) {                  \
                int c = la + 16*(ctb2+ci);                                      \
                bf16x8 bh2 = *(const bf16x8*)&sxv.xs[SB][0][c][8*lg + 32*sc];   \
                bf16x8 bl2 = *(const bf16x8*)&sxv.xs[SB][1][c][8*lg + 32*sc];   \
                _Pragma("unroll") for (int m = 0; m < 2; ++m) {                 \
                    acc2[m][ci] = MFMA16(al8[m], bh2, acc2[m][ci]);             \
                    acc2[m][ci] = MFMA16(ah[m], bl2, acc2[m][ci]);              \
                    acc2[m][ci] = MFMA16(ah[m], bh2, acc2[m][ci]);              \
                }                                                               \
            }                                                                   \
        }                                                                       \
    }

#define TILE_BODY(T, PXC, PXN, BUF)                                             \
{                                                                               \
    /* issue GEMM1 B-frag loads (L2 re-reads) */                                \
    float bx[4][8];                                                             \
    {                                                                           \
        int sb = (T)*TS + 16*nt1 + la; if (sb > S_-1) sb = S_-1;                \
        const float* bp = xn + (size_t)(8*lg)*S_ + sb;                          \
        _Pragma("unroll") for (int cc = 0; cc < 4; ++cc)                        \
        _Pragma("unroll") for (int i = 0; i < 8; ++i)                           \
            bx[cc][i] = bp[(size_t)(32*cc + i)*S_];                             \
    }                                                                           \
    /* issue px(T+1) (HBM first touch) */                                       \
    if ((T) + 1 < NTILE) {                                                      \
        int gs = ((T)+1)*TS + s0l;                                              \
        _Pragma("unroll") for (int r = 0; r < 4; ++r) {                         \
            const float* pr = xn + (size_t)(c0+r)*S_ + gs;                      \
            if (gs + 3 < S_) {                                                  \
                PXN[r][0]=pr[0]; PXN[r][1]=pr[1]; PXN[r][2]=pr[2]; PXN[r][3]=pr[3]; \
            } else {                                                            \
                _Pragma("unroll") for (int j = 0; j < 4; ++j)                   \
                    PXN[r][j] = (gs + j < S_) ? pr[j] : 0.f;                    \
            }                                                                   \
        }                                                                       \
    }                                                                           \
    /* P3(T-1): GEMM2 on previous tile (other xs buffer) */                     \
    if ((T) > 0) GEMM2_STEP((BUF)^1)                                            \
    /* stage xs[BUF] + alpha partials */                                        \
    {                                                                           \
        unsigned short hv[4][4], lv[4][4];                                      \
        float ssqp[4] = {0.f,0.f,0.f,0.f};                                      \
        float hdp[4]  = {0.f,0.f,0.f,0.f};                                      \
        _Pragma("unroll") for (int r = 0; r < 4; ++r)                           \
        _Pragma("unroll") for (int j = 0; j < 4; ++j) {                         \
            float f = PXC[r][j];                                                \
            split_bf(f, hv[r][j], lv[r][j]);                                    \
            ssqp[j] += f*f;                                                     \
            hdp[j]  += fmaxf(f, 0.f)*awr[r];                                    \
        }                                                                       \
        _Pragma("unroll") for (int r = 0; r < 4; ++r) {                         \
            us4 a = {hv[r][0],hv[r][1],hv[r][2],hv[r][3]};                      \
            us4 b = {lv[r][0],lv[r][1],lv[r][2],lv[r][3]};                      \
            *(us4*)&sxv.xs[BUF][0][c0+r][s0l] = a;                              \
            *(us4*)&sxv.xs[BUF][1][c0+r][s0l] = b;                              \
        }                                                                       \
        _Pragma("unroll") for (int j = 0; j < 4; ++j) {                         \
            ssqp[j] += __shfl_xor(ssqp[j], 16);                                 \
            ssqp[j] += __shfl_xor(ssqp[j], 32);                                 \
            hdp[j]  += __shfl_xor(hdp[j], 16);                                  \
            hdp[j]  += __shfl_xor(hdp[j], 32);                                  \
        }                                                                       \
        if (lg == 0) {                                                          \
            f32x4 a = {ssqp[0],ssqp[1],ssqp[2],ssqp[3]};                        \
            f32x4 b = {hdp[0],hdp[1],hdp[2],hdp[3]};                            \
            *(f32x4*)&s_ared[0][w][s0l] = a;                                    \
            *(f32x4*)&s_ared[1][w][s0l] = b;                                    \
        }                                                                       \
    }                                                                           \
    /* GEMM1(T): register-only B-frags */                                       \
    {                                                                           \
        bf16x8 bh[4], bl[4];                                                    \
        _Pragma("unroll") for (int cc = 0; cc < 4; ++cc)                        \
        _Pragma("unroll") for (int i = 0; i < 8; ++i) {                         \
            unsigned short hh, ll;                                              \
            split_bf(bx[cc][i], hh, ll);                                        \
            bh[cc][i] = (short)hh; bl[cc][i] = (short)ll;                       \
        }                                                                       \
        f32x4 d0 = {0.f,0.f,0.f,0.f}, d1 = {0.f,0.f,0.f,0.f};                   \
        _Pragma("unroll") for (int cc = 0; cc < 4; ++cc) {                      \
            d0 = MFMA16(cwlo[0][cc], bh[cc], d0);                               \
            d0 = MFMA16(cwhi[0][cc], bl[cc], d0);                               \
            d0 = MFMA16(cwhi[0][cc], bh[cc], d0);                               \
            d1 = MFMA16(cwlo[1][cc], bh[cc], d1);                               \
            d1 = MFMA16(cwhi[1][cc], bl[cc], d1);                               \
            d1 = MFMA16(cwhi[1][cc], bh[cc], d1);                               \
        }                                                                       \
        _Pragma("unroll") for (int i = 0; i < 4; ++i) {                         \
            s_d[16*mtb + 4*lg + i][16*nt1 + la]     = d0[i];                    \
            s_d[16*(mtb+1) + 4*lg + i][16*nt1 + la] = d1[i];                    \
        }                                                                       \
    }                                                                           \
    __syncthreads();  /* A */                                                   \
    /* P2: alpha finalize + softmax */                                          \
    {                                                                           \
        int j8 = lane & 7, q8 = lane >> 3;                                      \
        float ssq = s_ared[0][q8][8*w + j8];                                    \
        float hd  = s_ared[1][q8][8*w + j8];                                    \
        ssq += __shfl_xor(ssq, 8); ssq += __shfl_xor(ssq, 16); ssq += __shfl_xor(ssq, 32); \
        hd  += __shfl_xor(hd, 8);  hd  += __shfl_xor(hd, 16);  hd  += __shfl_xor(hd, 32);  \
        int sg = (T)*TS + 8*w + j8;                                             \
        float hm = (sg < S_) ? fmaxf(hd + bias, 0.f) : 0.f;                     \
        float al = hm / fmaxf(sqrtf(ssq), 1e-12f);                              \
        const float* drow = &s_d[lane][8*w];                                    \
        f32x4 dA = *(const f32x4*)drow;                                         \
        f32x4 dB = *(const f32x4*)(drow + 4);                                   \
        float uu[8];                                                            \
        _Pragma("unroll") for (int j = 0; j < 8; ++j) {                         \
            float alj = __shfl(al, j, 8);                                       \
            float hmj = __shfl(hm, j, 8);                                       \
            float dv = ((j < 4) ? dA[j] : dB[j-4]) * alj;                       \
            float e = __expf(dv);                                               \
            float sm = wave_sum64(e);                                           \
            float wv = e * hmj * __builtin_amdgcn_rcpf(sm);                     \
            wpart += wv;                                                        \
            uu[j] = wv * alj;                                                   \
        }                                                                       \
        bf16x8 h8, l8;                                                          \
        _Pragma("unroll") for (int j = 0; j < 8; ++j) {                         \
            unsigned short hh, ll;                                              \
            split_bf(uu[j], hh, ll);                                            \
            h8[j] = (short)hh; l8[j] = (short)ll;                               \
        }                                                                       \
        *(bf16x8*)&s_u[0][lane][8*w] = h8;                                      \
        *(bf16x8*)&s_u[1][lane][8*w] = l8;                                      \
    }                                                                           \
    __syncthreads();  /* C */                                                   \
}

    for (int tp = 0; tp < NTILE; tp += 2) {
        TILE_BODY(tp,     pxA, pxB, 0)
        TILE_BODY(tp + 1, pxB, pxA, 1)
    }
    // final P3(15): xs buffer 1
    GEMM2_STEP(1)

    // ================= epilogue =================
    s_wred[w][lane] = wpart;
    __syncthreads();
    if (tid < K_) {
        float v = 0.f;
        #pragma unroll
        for (int q = 0; q < 8; ++q) v += s_wred[q][tid];
        s_wsum[tid] = v;
    }
    __syncthreads();

    {
        #pragma unroll
        for (int m = 0; m < 2; ++m) {
            #pragma unroll
            for (int ci = 0; ci < 2; ++ci) {
                int c = la + 16 * (ctb2 + ci);
                #pragma unroll
                for (int i = 0; i < 4; ++i) {
                    int k = 16 * (mtb2 + m) + 4 * lg + i;
                    sxv.vl[k][c] = acc2[m][ci][i] - cent[k * C_ + c] * s_wsum[k];
                }
            }
        }
    }
    __syncthreads();

    // per-cluster row norm over c
    {
        int k = tid >> 3;
        int q = tid & 7;
        float ssq = 0.f;
        #pragma unroll
        for (int i = 0; i < 16; ++i) {
            float v = sxv.vl[k][q * 16 + i];
            ssq += v * v;
        }
        #pragma unroll
        for (int m = 1; m < 8; m <<= 1) ssq += __shfl_xor(ssq, m);
        if (q == 0) {
            float rs = 1.0f / fmaxf(sqrtf(ssq), 1e-12f);
            s_rs[k] = rs;
            s_wred[0][k] = ssq * rs * rs;
        }
    }
    __syncthreads();

    if (tid < 64) {
        float v = s_wred[0][tid];
        #pragma unroll
        for (int m = 1; m < 64; m <<= 1) v += __shfl_xor(v, m);
        if (tid == 0) {
            float n1 = sqrtf(v);
            float sc1 = 1.0f / fmaxf(n1, 1e-12f);
            float n2 = n1 * sc1;
            float sc2 = 1.0f / fmaxf(n2, 1e-12f);
            s_fin = sc1 * sc2;
        }
    }
    __syncthreads();

    {
        float fs = s_fin;
        float* on = out + (size_t)n * (K_ * C_);
        #pragma unroll
        for (int it = 0; it < 16; ++it) {
            int idx = tid + it * NTHREADS;
            int k = idx >> 7, c = idx & 127;
            on[idx] = sxv.vl[k][c] * s_rs[k] * fs;
        }
    }
}

extern "C" void kernel_launch(void* const* d_in, const int* in_sizes, int n_in,
                              void* d_out, int out_size, void* d_ws, size_t ws_size,
                              hipStream_t stream) {
    const float* x      = (const float*)d_in[0];
    const float* conv_w = (const float*)d_in[1];
    const float* cent   = (const float*)d_in[2];
    const float* aw     = (const float*)d_in[3];
    const float* ab     = (const float*)d_in[4];
    float* outp = (float*)d_out;

    vlad_mfma_kernel<<<N_, NTHREADS, 0, stream>>>(x, conv_w, cent, aw, ab, outp);
}